// Round 6
// baseline (343.625 us; speedup 1.0000x reference)
//
#include <hip/hip_runtime.h>
#include <math.h>

// ---------------------------------------------------------------------------
// AttentionModel on MI355X. Round 6:
//  - LSTM: xp eliminated; per-step kernel is fully register-resident
//    (A frags for whole K=512 in VGPRs, W streamed depth-2, no LDS/barriers),
//    cell fused in epilogue. 8 dispatches, grid 512 blocks each.
// ---------------------------------------------------------------------------

#define Bq 8
#define Tq 2048
#define Fq 257
#define Hq 256
#define Gq 1024          // 4*H
#define TH (Tq*Hq)       // 524288
#define KW 192           // k-window rows per 64-row t-tile
#define PLD 40           // P row stride (bf16)
#define KTLD 40          // KT row stride (bf16)
#define Mq (Bq*Tq)       // 16384

typedef __bf16 bf16_t;
typedef __bf16 bf16x8 __attribute__((ext_vector_type(8)));
typedef float f32x4 __attribute__((ext_vector_type(4)));

__device__ __forceinline__ float sigf(float x) { return 1.0f / (1.0f + __expf(-x)); }
__device__ __forceinline__ float tanh_f(float x) { return 1.0f - 2.0f / (__expf(2.0f * x) + 1.0f); }

// ------------------- batched fp32 -> bf16 convert (one dispatch) ------------
#define CV_X   (Mq*288)            // x padded 257->288
#define CV_FW  (256*288)           // feat_w padded
#define CV_WK  (1024*512)          // [k_Wih | k_Whh]  (rows g*256+j)
#define CV_WQ  (1024*512)          // [q_Wih | q_Whh]
#define CV_SC  (256*256)
#define CV_EN  (256*512)
#define CV_MK  (384*256)           // mask_w padded rows 257->384
#define CV_O1  CV_X
#define CV_O2  (CV_O1+CV_FW)
#define CV_O3  (CV_O2+CV_WK)
#define CV_O4  (CV_O3+CV_WQ)
#define CV_O5  (CV_O4+CV_SC)
#define CV_O6  (CV_O5+CV_EN)
#define CV_TOT (CV_O6+CV_MK)

__global__ __launch_bounds__(256) void cvt_all(
    const float* __restrict__ x, const float* __restrict__ feat_w,
    const float* __restrict__ kWih, const float* __restrict__ kWhh,
    const float* __restrict__ qWih, const float* __restrict__ qWhh,
    const float* __restrict__ scorew, const float* __restrict__ enhw,
    const float* __restrict__ maskw, bf16_t* __restrict__ dst)
{
    const int base = (blockIdx.x * 256 + threadIdx.x) * 8;
    if (base >= CV_TOT) return;
    bf16_t v[8];
#pragma unroll
    for (int e = 0; e < 8; ++e) {
        const int i = base + e;
        float f;
        if (i < CV_O1)      { const int r = i / 288, c = i - r * 288;
                              f = (c < Fq) ? x[(size_t)r * Fq + c] : 0.0f; }
        else if (i < CV_O2) { const int i2 = i - CV_O1, r = i2 / 288, c = i2 - r * 288;
                              f = (c < Fq) ? feat_w[r * Fq + c] : 0.0f; }
        else if (i < CV_O3) { const int i2 = i - CV_O2, r = i2 >> 9, c = i2 & 511;
                              f = (c < 256) ? kWih[r * 256 + c] : kWhh[r * 256 + c - 256]; }
        else if (i < CV_O4) { const int i2 = i - CV_O3, r = i2 >> 9, c = i2 & 511;
                              f = (c < 256) ? qWih[r * 256 + c] : qWhh[r * 256 + c - 256]; }
        else if (i < CV_O5) { f = scorew[i - CV_O4]; }
        else if (i < CV_O6) { f = enhw[i - CV_O5]; }
        else                { const int i2 = i - CV_O6, r = i2 >> 8, c = i2 & 255;
                              f = (r < Fq) ? maskw[r * 256 + c] : 0.0f; }
        v[e] = (bf16_t)f;
    }
    *(bf16x8*)(dst + base) = *(bf16x8*)v;
}

// fold the four LSTM bias vectors into one f32[2048]: [k | q], idx g*256+j
__global__ void bias_fold(const float* __restrict__ kbih, const float* __restrict__ kbhh,
                          const float* __restrict__ qbih, const float* __restrict__ qbhh,
                          float* __restrict__ out)
{
    const int i = blockIdx.x * 256 + threadIdx.x;   // 0..2047
    out[i] = (i < 1024) ? kbih[i] + kbhh[i] : qbih[i - 1024] + qbhh[i - 1024];
}

// ----------------------------- bf16 MFMA NT GEMM ----------------------------
// 128x128 tile, 4 waves (2x2 of 64x64), BK=32. A split in two K-segments.
template<int ACT, bool MULX, bool BF16OUT, bool F32OUT>
__device__ __forceinline__ void gemm_core(
    const bf16_t* __restrict__ A1, int lda1, int K1,
    const bf16_t* __restrict__ A2, int lda2, int K2,
    const bf16_t* __restrict__ W,
    const float* __restrict__ bias,
    const float* __restrict__ xm, int ldx,
    float* __restrict__ out, bf16_t* __restrict__ outbf, int ldo,
    int Nlog, int m0, int n0)
{
    __shared__ __align__(16) bf16_t As[128 * 32];
    __shared__ __align__(16) bf16_t Ws[128 * 32];
    const int tid = threadIdx.x;
    const int lane = tid & 63;
    const int wave = tid >> 6;
    const int wr = wave >> 1, wc = wave & 1;
    const int fr = lane & 15;
    const int fo = (lane >> 4) * 8;
    const int srow = tid >> 2;
    const int scol = (tid & 3) * 8;

    f32x4 acc[4][4] = {};

    const int K = K1 + K2;
    const int ldw = K;
    for (int k0 = 0; k0 < K; k0 += 32) {
        const bf16_t* Aseg; int kk, lda;
        if (k0 < K1) { Aseg = A1; kk = k0;      lda = lda1; }
        else         { Aseg = A2; kk = k0 - K1; lda = lda2; }
        const uint4 a0 = *(const uint4*)(Aseg + (size_t)(m0 + srow)      * lda + kk + scol);
        const uint4 a1 = *(const uint4*)(Aseg + (size_t)(m0 + srow + 64) * lda + kk + scol);
        const uint4 w0 = *(const uint4*)(W    + (size_t)(n0 + srow)      * ldw + k0 + scol);
        const uint4 w1 = *(const uint4*)(W    + (size_t)(n0 + srow + 64) * ldw + k0 + scol);
        __syncthreads();
        *(uint4*)&As[srow * 32 + scol]        = a0;
        *(uint4*)&As[(srow + 64) * 32 + scol] = a1;
        *(uint4*)&Ws[srow * 32 + scol]        = w0;
        *(uint4*)&Ws[(srow + 64) * 32 + scol] = w1;
        __syncthreads();
        bf16x8 af[4], bfr[4];
#pragma unroll
        for (int i = 0; i < 4; ++i) af[i]  = *(const bf16x8*)&As[(wr * 64 + i * 16 + fr) * 32 + fo];
#pragma unroll
        for (int j = 0; j < 4; ++j) bfr[j] = *(const bf16x8*)&Ws[(wc * 64 + j * 16 + fr) * 32 + fo];
#pragma unroll
        for (int i = 0; i < 4; ++i)
#pragma unroll
            for (int j = 0; j < 4; ++j)
                acc[i][j] = __builtin_amdgcn_mfma_f32_16x16x32_bf16(af[i], bfr[j], acc[i][j], 0, 0, 0);
    }

    const int rbase = (lane >> 4) * 4;
#pragma unroll
    for (int i = 0; i < 4; ++i) {
#pragma unroll
        for (int j = 0; j < 4; ++j) {
            const int n = n0 + wc * 64 + j * 16 + fr;
            if (n >= Nlog) continue;
            const float bv = bias ? bias[n] : 0.0f;
            const int m = m0 + wr * 64 + i * 16 + rbase;
#pragma unroll
            for (int r = 0; r < 4; ++r) {
                float v = acc[i][j][r] + bv;
                if (ACT == 1) v = tanh_f(v);
                else if (ACT == 2) v = sigf(v);
                if (MULX) v *= xm[(size_t)(m + r) * ldx + n];
                if (F32OUT) out[(size_t)(m + r) * ldo + n] = v;
                if (BF16OUT) outbf[(size_t)(m + r) * ldo + n] = (bf16_t)v;
            }
        }
    }
}

template<int ACT, bool MULX, bool BF16OUT, bool F32OUT>
__global__ __launch_bounds__(256) void gemm_mfma(
    const bf16_t* A1, int lda1, int K1, const bf16_t* A2, int lda2, int K2,
    const bf16_t* W, const float* bias, const float* xm, int ldx,
    float* out, bf16_t* outbf, int ldo, int Nlog)
{
    gemm_core<ACT, MULX, BF16OUT, F32OUT>(A1, lda1, K1, A2, lda2, K2, W, bias, xm, ldx,
                                          out, outbf, ldo, Nlog,
                                          blockIdx.y * 128, blockIdx.x * 128);
}

// ------------- LSTM step: register-resident GEMM + fused cell ---------------
// gates = hfeat_b @ Wih^T + h_prev @ Whh^T + bias; W packed rows (g*256+j),
// cols [Wih(256)|Whh(256)]. Per block: 64 t-rows x 32 j x 4 gates.
// A frags for all NC k-chunks live in VGPRs; W streamed depth-2. No LDS.
template<int NC>
__global__ __launch_bounds__(256) void lstm_step(
    const bf16_t* __restrict__ hfb,                                  // hfeat + b*TH
    const bf16_t* __restrict__ hkp, const bf16_t* __restrict__ hqp,  // prev h (b>0)
    const bf16_t* __restrict__ Wall, const float* __restrict__ bias_all,
    float* __restrict__ cst,
    bf16_t* __restrict__ hk, bf16_t* __restrict__ hq)
{
    const int z = blockIdx.z;
    const bf16_t* hprev = z ? hqp : hkp;
    const bf16_t* Wz = Wall + (size_t)z * (1024 * 512);
    float* c = cst + (size_t)z * TH;
    bf16_t* hout = z ? hq : hk;

    const int tid = threadIdx.x, lane = tid & 63, wave = tid >> 6;
    const int wr = wave >> 1, wc = wave & 1;
    const int fr = lane & 15, rg = lane >> 4, fo = rg * 8;
    const int m0 = blockIdx.y * 64;
    const int j = blockIdx.x * 32 + wc * 16 + fr;

    // ---- A fragments for the whole step (32 outstanding loads) ----
    bf16x8 a[2][NC];
#pragma unroll
    for (int i = 0; i < 2; ++i) {
        const size_t rbase = (size_t)(m0 + wr * 32 + i * 16 + fr) * Hq + fo;
#pragma unroll
        for (int t = 0; t < 8; ++t)
            a[i][t] = *(const bf16x8*)(hfb + rbase + t * 32);
        if (NC == 16) {
#pragma unroll
            for (int t = 8; t < 16; ++t)
                a[i][t] = *(const bf16x8*)(hprev + rbase + (t - 8) * 32);
        }
    }

    // ---- W stream, depth-2 pipeline ----
    const bf16_t* wp[4];
#pragma unroll
    for (int g = 0; g < 4; ++g) wp[g] = Wz + (size_t)(g * 256 + j) * 512 + fo;

    f32x4 acc[2][4] = {};
    bf16x8 wA[4], wB[4];
#pragma unroll
    for (int g = 0; g < 4; ++g) wA[g] = *(const bf16x8*)(wp[g]);
#pragma unroll
    for (int t = 0; t < NC; ++t) {
        if (t + 1 < NC) {
#pragma unroll
            for (int g = 0; g < 4; ++g) {
                if (t & 1) wA[g] = *(const bf16x8*)(wp[g] + (t + 1) * 32);
                else       wB[g] = *(const bf16x8*)(wp[g] + (t + 1) * 32);
            }
        }
#pragma unroll
        for (int i = 0; i < 2; ++i)
#pragma unroll
            for (int g = 0; g < 4; ++g)
                acc[i][g] = __builtin_amdgcn_mfma_f32_16x16x32_bf16(
                    a[i][t], (t & 1) ? wB[g] : wA[g], acc[i][g], 0, 0, 0);
    }

    // ---- cell epilogue: thread owns 4 gates of col j for 8 rows ----
    float bs[4];
#pragma unroll
    for (int g = 0; g < 4; ++g) bs[g] = bias_all[z * 1024 + g * 256 + j];
#pragma unroll
    for (int i = 0; i < 2; ++i)
#pragma unroll
        for (int r = 0; r < 4; ++r) {
            const int trow = m0 + wr * 32 + i * 16 + rg * 4 + r;
            const size_t ix = (size_t)trow * Hq + j;
            const float gi = acc[i][0][r] + bs[0];
            const float gf = acc[i][1][r] + bs[1];
            const float gg = acc[i][2][r] + bs[2];
            const float go = acc[i][3][r] + bs[3];
            const float cn = sigf(gf) * c[ix] + sigf(gi) * tanh_f(gg);
            c[ix] = cn;
            hout[ix] = (bf16_t)(sigf(go) * tanh_f(cn));
        }
}

// ----------------------- fused banded attention (unchanged) -----------------
__global__ __launch_bounds__(256) void band_fused(
    const bf16_t* __restrict__ qsbf, const bf16_t* __restrict__ kbf,
    float* __restrict__ out1, bf16_t* __restrict__ c_att)
{
    __shared__ __align__(16) bf16_t Ks[8 * KW * 32];     // 98304 B, [h/32][j][32]
    __shared__ __align__(16) bf16_t P[6 * 64 * PLD];     // 30720 B
    __shared__ __align__(16) bf16_t KT[256 * KTLD];      // 20480 B

    const int b = blockIdx.y;
    const int t0 = blockIdx.x * 64;
    const int u0 = t0 - 128;
    const int tid = threadIdx.x, lane = tid & 63, w = tid >> 6;
    const int fr = lane & 15, rg = lane >> 4, fo = rg * 8;
    const size_t kbase = (size_t)b * Tq;

#pragma unroll
    for (int it = 0; it < 24; ++it) {
        const int idx = it * 256 + tid;
        const int n  = idx >> 5;
        const int c8 = (idx & 31) * 8;
        uint4 v = {0, 0, 0, 0};
        const int u = u0 + n;
        if (u >= 0) v = *(const uint4*)(kbf + (kbase + u) * (size_t)Hq + c8);
        *(uint4*)&Ks[((c8 >> 5) * KW + n) * 32 + (c8 & 31)] = v;
    }
    __syncthreads();

    f32x4 acc[12] = {};
    const bf16_t* qrow = qsbf + (kbase + t0 + 16 * w + fr) * (size_t)Hq;
#pragma unroll
    for (int ks = 0; ks < 8; ++ks) {
        const bf16x8 aq = *(const bf16x8*)(qrow + ks * 32 + fo);
#pragma unroll
        for (int jf = 0; jf < 12; ++jf) {
            const bf16x8 bk = *(const bf16x8*)&Ks[(ks * KW + jf * 16 + fr) * 32 + fo];
            acc[jf] = __builtin_amdgcn_mfma_f32_16x16x32_bf16(aq, bk, acc[jf], 0, 0, 0);
        }
    }

    const int jmin = (128 - t0) > 0 ? (128 - t0) : 0;
    float mx[4] = {-3e38f, -3e38f, -3e38f, -3e38f};
#pragma unroll
    for (int jf = 0; jf < 12; ++jf)
#pragma unroll
        for (int r = 0; r < 4; ++r) {
            const int i = 16 * w + rg * 4 + r;
            const int j = jf * 16 + fr;
            if (j >= i && j <= i + 128 && j >= jmin)
                mx[r] = fmaxf(mx[r], acc[jf][r]);
        }
#pragma unroll
    for (int d = 1; d < 16; d <<= 1)
#pragma unroll
        for (int r = 0; r < 4; ++r) mx[r] = fmaxf(mx[r], __shfl_xor(mx[r], d));

    float ex[12][4];
    float sm[4] = {0.0f, 0.0f, 0.0f, 0.0f};
#pragma unroll
    for (int jf = 0; jf < 12; ++jf)
#pragma unroll
        for (int r = 0; r < 4; ++r) {
            const int i = 16 * w + rg * 4 + r;
            const int j = jf * 16 + fr;
            const bool v = (j >= i && j <= i + 128 && j >= jmin);
            const float e = v ? __expf(acc[jf][r] - mx[r]) : 0.0f;
            ex[jf][r] = e;
            sm[r] += e;
        }
#pragma unroll
    for (int d = 1; d < 16; d <<= 1)
#pragma unroll
        for (int r = 0; r < 4; ++r) sm[r] += __shfl_xor(sm[r], d);
    float inv[4];
#pragma unroll
    for (int r = 0; r < 4; ++r) inv[r] = 1.0f / (sm[r] + 1e-10f);

#pragma unroll
    for (int jf = 0; jf < 12; ++jf)
#pragma unroll
        for (int r = 0; r < 4; ++r) {
            const int i = 16 * w + rg * 4 + r;
            const int j = jf * 16 + fr;
            const float wv = ex[jf][r] * inv[r];
            if (u0 + j >= 0)
                out1[(kbase + t0 + i) * (size_t)Tq + (u0 + j)] = wv;
            P[((j >> 5) * 64 + i) * PLD + (j & 31)] = (bf16_t)wv;
        }

    {
        const int c4l = (u0 > 0 ? u0 : 0) >> 2;
        const int c4r = (u0 + KW) >> 2;
        const float4 z4 = {0.0f, 0.0f, 0.0f, 0.0f};
        for (int rr = 0; rr < 16; ++rr) {
            float* rowp = out1 + (kbase + t0 + 16 * w + rr) * (size_t)Tq;
            for (int c4 = lane; c4 < c4l; c4 += 64)
                *(float4*)(rowp + 4 * c4) = z4;
            for (int c4 = c4r + lane; c4 < Tq / 4; c4 += 64)
                *(float4*)(rowp + 4 * c4) = z4;
        }
    }

    f32x4 cacc[16] = {};
    for (int jc = 0; jc < 6; ++jc) {
        __syncthreads();
#pragma unroll
        for (int it = 0; it < 4; ++it) {
            const int idx = it * 256 + tid;
            const int jl = idx >> 5;
            const int hc = (idx & 31) * 8;
            const bf16x8 kv = *(const bf16x8*)&Ks[((hc >> 5) * KW + jc * 32 + jl) * 32 + (hc & 31)];
#pragma unroll
            for (int e = 0; e < 8; ++e) KT[(hc + e) * KTLD + jl] = kv[e];
        }
        __syncthreads();
        const bf16x8 pa = *(const bf16x8*)&P[(jc * 64 + 16 * w + fr) * PLD + fo];
#pragma unroll
        for (int hf = 0; hf < 16; ++hf) {
            const bf16x8 bk = *(const bf16x8*)&KT[(hf * 16 + fr) * KTLD + fo];
            cacc[hf] = __builtin_amdgcn_mfma_f32_16x16x32_bf16(pa, bk, cacc[hf], 0, 0, 0);
        }
    }

#pragma unroll
    for (int hf = 0; hf < 16; ++hf)
#pragma unroll
        for (int r = 0; r < 4; ++r) {
            const int i = 16 * w + rg * 4 + r;
            c_att[(kbase + t0 + i) * (size_t)Hq + hf * 16 + fr] = (bf16_t)cacc[hf][r];
        }
}

// ---------------------------------------------------------------------------
extern "C" void kernel_launch(void* const* d_in, const int* in_sizes, int n_in,
                              void* d_out, int out_size, void* d_ws, size_t ws_size,
                              hipStream_t stream)
{
    (void)in_sizes; (void)n_in; (void)out_size; (void)ws_size;
    const float* x        = (const float*)d_in[0];
    const float* feat_w   = (const float*)d_in[1];
    const float* feat_b   = (const float*)d_in[2];
    const float* k_Wih    = (const float*)d_in[3];
    const float* k_Whh    = (const float*)d_in[4];
    const float* k_bih    = (const float*)d_in[5];
    const float* k_bhh    = (const float*)d_in[6];
    const float* q_Wih    = (const float*)d_in[7];
    const float* q_Whh    = (const float*)d_in[8];
    const float* q_bih    = (const float*)d_in[9];
    const float* q_bhh    = (const float*)d_in[10];
    const float* score_w  = (const float*)d_in[11];
    const float* enhance_w= (const float*)d_in[12];
    const float* enhance_b= (const float*)d_in[13];
    const float* mask_w   = (const float*)d_in[14];
    const float* mask_b   = (const float*)d_in[15];

    float* out0 = (float*)d_out;                         // (8,2048,257)
    float* out1 = out0 + (size_t)Bq * Tq * Fq;           // (8,2048,2048)

    // ---- workspace ----
    float* cst      = (float*)d_ws;                      // 2*TH f32 (c states)
    float* bias_all = cst + (size_t)2 * TH;              // 2048 f32
    bf16_t* cvd = (bf16_t*)(bias_all + 2048);
    bf16_t* xbf     = cvd;                               // reused as qsbf later
    bf16_t* featw   = cvd + CV_O1;
    bf16_t* Wall    = cvd + CV_O2;                       // 2048x512 [k;q]x[Wih|Whh]
    bf16_t* scw     = cvd + CV_O4;
    bf16_t* enw     = cvd + CV_O5;
    bf16_t* mkw     = cvd + CV_O6;
    bf16_t* hfeatbf = cvd + CV_TOT;                      // Mq*256 (reused as out_h)
    bf16_t* hkbf    = hfeatbf + (size_t)Mq * Hq;         // 8*TH
    bf16_t* hqbf    = hkbf + (size_t)Bq * TH;            // 8*TH
    bf16_t* cattb   = hqbf + (size_t)Bq * TH;            // Mq*256

    hipMemsetAsync(cst, 0, (size_t)2 * TH * sizeof(float), stream);

    cvt_all<<<CV_TOT / 8 / 256, 256, 0, stream>>>(
        x, feat_w, k_Wih, k_Whh, q_Wih, q_Whh, score_w, enhance_w, mask_w, cvd);
    bias_fold<<<8, 256, 0, stream>>>(k_bih, k_bhh, q_bih, q_bhh, bias_all);

    // 1) feat: hfeatbf = tanh(x @ feat_w^T + feat_b)
    gemm_mfma<1, false, true, false><<<dim3(2, Mq / 128), 256, 0, stream>>>(
        xbf, 288, 288, nullptr, 0, 0, featw, feat_b, nullptr, 0,
        nullptr, hfeatbf, Hq, 1 << 30);

    // 2) LSTM k & q: 8 register-resident fused steps
    for (int b = 0; b < Bq; ++b) {
        if (b == 0)
            lstm_step<8><<<dim3(8, Tq / 64, 2), 256, 0, stream>>>(
                hfeatbf, nullptr, nullptr, Wall, bias_all, cst, hkbf, hqbf);
        else
            lstm_step<16><<<dim3(8, Tq / 64, 2), 256, 0, stream>>>(
                hfeatbf + (size_t)b * TH,
                hkbf + (size_t)(b - 1) * TH, hqbf + (size_t)(b - 1) * TH,
                Wall, bias_all, cst,
                hkbf + (size_t)b * TH, hqbf + (size_t)b * TH);
    }

    // 3) score: qsbf = q @ score_w^T  (bf16, reuses xbf)
    bf16_t* qsbf = xbf;
    gemm_mfma<0, false, true, false><<<dim3(2, Mq / 128), 256, 0, stream>>>(
        hqbf, Hq, Hq, nullptr, 0, 0, scw, nullptr, nullptr, 0,
        nullptr, qsbf, Hq, 1 << 30);

    // 4+5) fused banded softmax + PV; writes full out1 rows
    band_fused<<<dim3(Tq / 64, Bq), 256, 0, stream>>>(qsbf, hkbf, out1, cattb);

    // 6) enhance: out_h = tanh([c, q] @ enhance_w^T + b)  (bf16, reuses hfeatbf)
    bf16_t* outh = hfeatbf;
    gemm_mfma<1, false, true, false><<<dim3(2, Mq / 128), 256, 0, stream>>>(
        cattb, Hq, Hq, hqbf, Hq, Hq, enw, enhance_b, nullptr, 0,
        nullptr, outh, Hq, 1 << 30);

    // 7) mask + final: out0 = x * sigmoid(out_h @ mask_w^T + mask_b)
    gemm_mfma<2, true, false, true><<<dim3(3, Mq / 128), 256, 0, stream>>>(
        outh, Hq, Hq, nullptr, 0, 0, mkw, mask_b, x, Fq,
        out0, nullptr, Fq, Fq);
}

// Round 7
// 254.102 us; speedup vs baseline: 1.3523x; 1.3523x over previous
//
#include <hip/hip_runtime.h>
#include <math.h>

// ---------------------------------------------------------------------------
// AttentionModel on MI355X. Round 7:
//  - LSTM reverted to round-5 structure (xp GEMM + pipelined LDS steps)
//  - all dense GEMMs re-tiled 64x128 with register-prefetch pipeline
//    (2-3 blocks/CU instead of 1; global latency hidden under MFMA)
// ---------------------------------------------------------------------------

#define Bq 8
#define Tq 2048
#define Fq 257
#define Hq 256
#define Gq 1024          // 4*H
#define TH (Tq*Hq)       // 524288
#define KW 192           // k-window rows per 64-row t-tile
#define PLD 40           // P row stride (bf16)
#define KTLD 40          // KT row stride (bf16)
#define Mq (Bq*Tq)       // 16384

typedef __bf16 bf16_t;
typedef __bf16 bf16x8 __attribute__((ext_vector_type(8)));
typedef float f32x4 __attribute__((ext_vector_type(4)));

__device__ __forceinline__ float sigf(float x) { return 1.0f / (1.0f + __expf(-x)); }
__device__ __forceinline__ float tanh_f(float x) { return 1.0f - 2.0f / (__expf(2.0f * x) + 1.0f); }

// ------------------- batched fp32 -> bf16 convert (one dispatch) ------------
#define CV_X   (Mq*288)            // x padded 257->288
#define CV_FW  (256*288)           // feat_w padded
#define CV_WIH (2048*256)          // [k_Wih ; q_Wih]   rows: z*1024 + g*256 + j
#define CV_WHH (2048*256)          // [k_Whh ; q_Whh]
#define CV_SC  (256*256)
#define CV_EN  (256*512)
#define CV_MK  (384*256)           // mask_w padded rows 257->384
#define CV_O1  CV_X
#define CV_O2  (CV_O1+CV_FW)
#define CV_O3  (CV_O2+CV_WIH)
#define CV_O4  (CV_O3+CV_WHH)
#define CV_O5  (CV_O4+CV_SC)
#define CV_O6  (CV_O5+CV_EN)
#define CV_TOT (CV_O6+CV_MK)       // 6,135,808

__global__ __launch_bounds__(256) void cvt_all(
    const float* __restrict__ x, const float* __restrict__ feat_w,
    const float* __restrict__ kWih, const float* __restrict__ kWhh,
    const float* __restrict__ qWih, const float* __restrict__ qWhh,
    const float* __restrict__ scorew, const float* __restrict__ enhw,
    const float* __restrict__ maskw, bf16_t* __restrict__ dst)
{
    const int base = (blockIdx.x * 256 + threadIdx.x) * 8;
    if (base >= CV_TOT) return;
    bf16_t v[8];
#pragma unroll
    for (int e = 0; e < 8; ++e) {
        const int i = base + e;
        float f;
        if (i < CV_O1)      { const int r = i / 288, c = i - r * 288;
                              f = (c < Fq) ? x[(size_t)r * Fq + c] : 0.0f; }
        else if (i < CV_O2) { const int i2 = i - CV_O1, r = i2 / 288, c = i2 - r * 288;
                              f = (c < Fq) ? feat_w[r * Fq + c] : 0.0f; }
        else if (i < CV_O3) { const int i2 = i - CV_O2, r = i2 >> 8, c = i2 & 255;
                              f = (r < 1024) ? kWih[r * 256 + c] : qWih[(r - 1024) * 256 + c]; }
        else if (i < CV_O4) { const int i2 = i - CV_O3, r = i2 >> 8, c = i2 & 255;
                              f = (r < 1024) ? kWhh[r * 256 + c] : qWhh[(r - 1024) * 256 + c]; }
        else if (i < CV_O5) { f = scorew[i - CV_O4]; }
        else if (i < CV_O6) { f = enhw[i - CV_O5]; }
        else                { const int i2 = i - CV_O6, r = i2 >> 8, c = i2 & 255;
                              f = (r < Fq) ? maskw[r * 256 + c] : 0.0f; }
        v[e] = (bf16_t)f;
    }
    *(bf16x8*)(dst + base) = *(bf16x8*)v;
}

// fold the four LSTM bias vectors into one f32[2048]: [k | q], idx g*256+j
__global__ void bias_fold(const float* __restrict__ kbih, const float* __restrict__ kbhh,
                          const float* __restrict__ qbih, const float* __restrict__ qbhh,
                          float* __restrict__ out)
{
    const int i = blockIdx.x * 256 + threadIdx.x;   // 0..2047
    out[i] = (i < 1024) ? kbih[i] + kbhh[i] : qbih[i - 1024] + qbhh[i - 1024];
}

// ---------------- bf16 MFMA NT GEMM, 64x128 tile, pipelined -----------------
// C[m,n] = sum_k A[m,k] * W[n,k]; A split in two K-segments; W packed N x K.
// 4 waves = 2x2 of (32m x 64n). Register-prefetch of k+1 under MFMA of k.
__device__ __forceinline__ const bf16_t* seg_ptr(
    const bf16_t* __restrict__ A1, int lda1, int K1,
    const bf16_t* __restrict__ A2, int lda2, int row, int k, int col8)
{
    return (k < K1) ? A1 + (size_t)row * lda1 + k + col8
                    : A2 + (size_t)row * lda2 + (k - K1) + col8;
}

template<int ACT, bool MULX, bool BF16OUT, bool F32OUT>
__global__ __launch_bounds__(256) void gemm_mfma(
    const bf16_t* __restrict__ A1, int lda1, int K1,
    const bf16_t* __restrict__ A2, int lda2, int K2,
    const bf16_t* __restrict__ W,
    const float* __restrict__ bias,
    const float* __restrict__ xm, int ldx,
    float* __restrict__ out, bf16_t* __restrict__ outbf, int ldo, int Nlog)
{
    __shared__ __align__(16) bf16_t As[64 * 32];     // 4 KB
    __shared__ __align__(16) bf16_t Ws[128 * 32];    // 8 KB
    const int tid = threadIdx.x;
    const int lane = tid & 63;
    const int wave = tid >> 6;
    const int wr = wave >> 1, wc = wave & 1;
    const int fr = lane & 15;
    const int fo = (lane >> 4) * 8;
    const int srow = tid >> 2;
    const int scol = (tid & 3) * 8;
    const int m0 = blockIdx.y * 64, n0 = blockIdx.x * 128;

    const int K = K1 + K2;
    const int ldw = K;

    uint4 ar = *(const uint4*)seg_ptr(A1, lda1, K1, A2, lda2, m0 + srow, 0, scol);
    uint4 w0 = *(const uint4*)(W + (size_t)(n0 + srow)      * ldw + scol);
    uint4 w1 = *(const uint4*)(W + (size_t)(n0 + srow + 64) * ldw + scol);

    f32x4 acc[2][4] = {};
    for (int k0 = 0; k0 < K; k0 += 32) {
        __syncthreads();                // prior LDS reads done
        *(uint4*)&As[srow * 32 + scol]        = ar;
        *(uint4*)&Ws[srow * 32 + scol]        = w0;
        *(uint4*)&Ws[(srow + 64) * 32 + scol] = w1;
        if (k0 + 32 < K) {              // prefetch k+1 (hides under MFMA below)
            ar = *(const uint4*)seg_ptr(A1, lda1, K1, A2, lda2, m0 + srow, k0 + 32, scol);
            w0 = *(const uint4*)(W + (size_t)(n0 + srow)      * ldw + k0 + 32 + scol);
            w1 = *(const uint4*)(W + (size_t)(n0 + srow + 64) * ldw + k0 + 32 + scol);
        }
        __syncthreads();
        bf16x8 af[2], bfr[4];
#pragma unroll
        for (int i = 0; i < 2; ++i) af[i]  = *(const bf16x8*)&As[(wr * 32 + i * 16 + fr) * 32 + fo];
#pragma unroll
        for (int j = 0; j < 4; ++j) bfr[j] = *(const bf16x8*)&Ws[(wc * 64 + j * 16 + fr) * 32 + fo];
#pragma unroll
        for (int i = 0; i < 2; ++i)
#pragma unroll
            for (int j = 0; j < 4; ++j)
                acc[i][j] = __builtin_amdgcn_mfma_f32_16x16x32_bf16(af[i], bfr[j], acc[i][j], 0, 0, 0);
    }

    const int rbase = (lane >> 4) * 4;
#pragma unroll
    for (int i = 0; i < 2; ++i) {
#pragma unroll
        for (int j = 0; j < 4; ++j) {
            const int n = n0 + wc * 64 + j * 16 + fr;
            if (n >= Nlog) continue;
            const float bv = bias ? bias[n] : 0.0f;
            const int m = m0 + wr * 32 + i * 16 + rbase;
#pragma unroll
            for (int r = 0; r < 4; ++r) {
                float v = acc[i][j][r] + bv;
                if (ACT == 1) v = tanh_f(v);
                else if (ACT == 2) v = sigf(v);
                if (MULX) v *= xm[(size_t)(m + r) * ldx + n];
                if (F32OUT) out[(size_t)(m + r) * ldo + n] = v;
                if (BF16OUT) outbf[(size_t)(m + r) * ldo + n] = (bf16_t)v;
            }
        }
    }
}

// --------------- LSTM step: h_prev @ Whh^T + xp, cell fused ------------------
// 64 rows x (32 j x 4 gates) per block; grid (8, 32, 2) = 512 blocks.
// Pipelined K-loop (K=256): reg-stage next iter's loads under current MFMA.
__global__ __launch_bounds__(256) void lstm_step(
    const bf16_t* __restrict__ hkp, const bf16_t* __restrict__ hqp,   // null at b=0
    const bf16_t* __restrict__ Whh_all,                               // 2048x256 [k;q]
    const float* __restrict__ xp_b,                                   // Tq x 2048 (this b)
    float* __restrict__ ck, float* __restrict__ cq,
    bf16_t* __restrict__ hk, bf16_t* __restrict__ hq)
{
    __shared__ __align__(16) bf16_t As[64 * 32];    // 4 KB
    __shared__ __align__(16) bf16_t Ws[128 * 32];   // 8 KB
    const int z = blockIdx.z;
    const bf16_t* hprev = z ? hqp : hkp;
    const bf16_t* Wbase = Whh_all + (size_t)z * 1024 * 256;
    float* c     = z ? cq : ck;
    bf16_t* hout = z ? hq : hk;

    const int tid = threadIdx.x, lane = tid & 63, wave = tid >> 6;
    const int wr = wave >> 1, wc = wave & 1;
    const int fr = lane & 15, rg = lane >> 4, fo = rg * 8;
    const int m0 = blockIdx.y * 64;
    const int jb = blockIdx.x * 32;

    f32x4 acc[2][4] = {};

    if (hprev) {
        const int arow = tid >> 2, acol = (tid & 3) * 8;
        const int s0 = tid >> 2, s1 = s0 + 64;
        const int wn0 = ((s0 >> 5) * 256) + jb + (s0 & 31);
        const int wn1 = ((s1 >> 5) * 256) + jb + (s1 & 31);
        uint4 ar  = *(const uint4*)(hprev + (size_t)(m0 + arow) * Hq + acol);
        uint4 w0r = *(const uint4*)(Wbase + (size_t)wn0 * 256 + acol);
        uint4 w1r = *(const uint4*)(Wbase + (size_t)wn1 * 256 + acol);
#pragma unroll
        for (int t = 0; t < 8; ++t) {
            if (t) __syncthreads();                  // prior LDS reads done
            *(uint4*)&As[arow * 32 + acol] = ar;
            *(uint4*)&Ws[s0 * 32 + acol]   = w0r;
            *(uint4*)&Ws[s1 * 32 + acol]   = w1r;
            if (t < 7) {                              // prefetch next k-slice
                const int k = (t + 1) * 32;
                ar  = *(const uint4*)(hprev + (size_t)(m0 + arow) * Hq + k + acol);
                w0r = *(const uint4*)(Wbase + (size_t)wn0 * 256 + k + acol);
                w1r = *(const uint4*)(Wbase + (size_t)wn1 * 256 + k + acol);
            }
            __syncthreads();
            bf16x8 af[2], bg[4];
#pragma unroll
            for (int i = 0; i < 2; ++i) af[i] = *(const bf16x8*)&As[(wr * 32 + i * 16 + fr) * 32 + fo];
#pragma unroll
            for (int g = 0; g < 4; ++g) bg[g] = *(const bf16x8*)&Ws[(g * 32 + wc * 16 + fr) * 32 + fo];
#pragma unroll
            for (int i = 0; i < 2; ++i)
#pragma unroll
                for (int g = 0; g < 4; ++g)
                    acc[i][g] = __builtin_amdgcn_mfma_f32_16x16x32_bf16(af[i], bg[g], acc[i][g], 0, 0, 0);
        }
    }

    // epilogue: thread owns 4 gates of column j for 8 rows (2 frags x 4)
    const int j = jb + wc * 16 + fr;
#pragma unroll
    for (int i = 0; i < 2; ++i) {
#pragma unroll
        for (int r = 0; r < 4; ++r) {
            const int t = m0 + wr * 32 + i * 16 + rg * 4 + r;
            const float* xpr = xp_b + (size_t)t * 2048 + (size_t)z * 1024;
            const float gi = acc[i][0][r] + xpr[j];
            const float gf = acc[i][1][r] + xpr[256 + j];
            const float gg = acc[i][2][r] + xpr[512 + j];
            const float go = acc[i][3][r] + xpr[768 + j];
            const size_t ix = (size_t)t * Hq + j;
            const float cn = sigf(gf) * c[ix] + sigf(gi) * tanh_f(gg);
            c[ix] = cn;
            hout[ix] = (bf16_t)(sigf(go) * tanh_f(cn));
        }
    }
}

// ----------------------- fused banded attention (unchanged) -----------------
__global__ __launch_bounds__(256) void band_fused(
    const bf16_t* __restrict__ qsbf, const bf16_t* __restrict__ kbf,
    float* __restrict__ out1, bf16_t* __restrict__ c_att)
{
    __shared__ __align__(16) bf16_t Ks[8 * KW * 32];     // 98304 B, [h/32][j][32]
    __shared__ __align__(16) bf16_t P[6 * 64 * PLD];     // 30720 B
    __shared__ __align__(16) bf16_t KT[256 * KTLD];      // 20480 B

    const int b = blockIdx.y;
    const int t0 = blockIdx.x * 64;
    const int u0 = t0 - 128;
    const int tid = threadIdx.x, lane = tid & 63, w = tid >> 6;
    const int fr = lane & 15, rg = lane >> 4, fo = rg * 8;
    const size_t kbase = (size_t)b * Tq;

#pragma unroll
    for (int it = 0; it < 24; ++it) {
        const int idx = it * 256 + tid;
        const int n  = idx >> 5;
        const int c8 = (idx & 31) * 8;
        uint4 v = {0, 0, 0, 0};
        const int u = u0 + n;
        if (u >= 0) v = *(const uint4*)(kbf + (kbase + u) * (size_t)Hq + c8);
        *(uint4*)&Ks[((c8 >> 5) * KW + n) * 32 + (c8 & 31)] = v;
    }
    __syncthreads();

    f32x4 acc[12] = {};
    const bf16_t* qrow = qsbf + (kbase + t0 + 16 * w + fr) * (size_t)Hq;
#pragma unroll
    for (int ks = 0; ks < 8; ++ks) {
        const bf16x8 aq = *(const bf16x8*)(qrow + ks * 32 + fo);
#pragma unroll
        for (int jf = 0; jf < 12; ++jf) {
            const bf16x8 bk = *(const bf16x8*)&Ks[(ks * KW + jf * 16 + fr) * 32 + fo];
            acc[jf] = __builtin_amdgcn_mfma_f32_16x16x32_bf16(aq, bk, acc[jf], 0, 0, 0);
        }
    }

    const int jmin = (128 - t0) > 0 ? (128 - t0) : 0;
    float mx[4] = {-3e38f, -3e38f, -3e38f, -3e38f};
#pragma unroll
    for (int jf = 0; jf < 12; ++jf)
#pragma unroll
        for (int r = 0; r < 4; ++r) {
            const int i = 16 * w + rg * 4 + r;
            const int j = jf * 16 + fr;
            if (j >= i && j <= i + 128 && j >= jmin)
                mx[r] = fmaxf(mx[r], acc[jf][r]);
        }
#pragma unroll
    for (int d = 1; d < 16; d <<= 1)
#pragma unroll
        for (int r = 0; r < 4; ++r) mx[r] = fmaxf(mx[r], __shfl_xor(mx[r], d));

    float ex[12][4];
    float sm[4] = {0.0f, 0.0f, 0.0f, 0.0f};
#pragma unroll
    for (int jf = 0; jf < 12; ++jf)
#pragma unroll
        for (int r = 0; r < 4; ++r) {
            const int i = 16 * w + rg * 4 + r;
            const int j = jf * 16 + fr;
            const bool v = (j >= i && j <= i + 128 && j >= jmin);
            const float e = v ? __expf(acc[jf][r] - mx[r]) : 0.0f;
            ex[jf][r] = e;
            sm[r] += e;
        }
#pragma unroll
    for (int d = 1; d < 16; d <<= 1)
#pragma unroll
        for (int r = 0; r < 4; ++r) sm[r] += __shfl_xor(sm[r], d);
    float inv[4];
#pragma unroll
    for (int r = 0; r < 4; ++r) inv[r] = 1.0f / (sm[r] + 1e-10f);

#pragma unroll
    for (int jf = 0; jf < 12; ++jf)
#pragma unroll
        for (int r = 0; r < 4; ++r) {
            const int i = 16 * w + rg * 4 + r;
            const int j = jf * 16 + fr;
            const float wv = ex[jf][r] * inv[r];
            if (u0 + j >= 0)
                out1[(kbase + t0 + i) * (size_t)Tq + (u0 + j)] = wv;
            P[((j >> 5) * 64 + i) * PLD + (j & 31)] = (bf16_t)wv;
        }

    {
        const int c4l = (u0 > 0 ? u0 : 0) >> 2;
        const int c4r = (u0 + KW) >> 2;
        const float4 z4 = {0.0f, 0.0f, 0.0f, 0.0f};
        for (int rr = 0; rr < 16; ++rr) {
            float* rowp = out1 + (kbase + t0 + 16 * w + rr) * (size_t)Tq;
            for (int c4 = lane; c4 < c4l; c4 += 64)
                *(float4*)(rowp + 4 * c4) = z4;
            for (int c4 = c4r + lane; c4 < Tq / 4; c4 += 64)
                *(float4*)(rowp + 4 * c4) = z4;
        }
    }

    f32x4 cacc[16] = {};
    for (int jc = 0; jc < 6; ++jc) {
        __syncthreads();
#pragma unroll
        for (int it = 0; it < 4; ++it) {
            const int idx = it * 256 + tid;
            const int jl = idx >> 5;
            const int hc = (idx & 31) * 8;
            const bf16x8 kv = *(const bf16x8*)&Ks[((hc >> 5) * KW + jc * 32 + jl) * 32 + (hc & 31)];
#pragma unroll
            for (int e = 0; e < 8; ++e) KT[(hc + e) * KTLD + jl] = kv[e];
        }
        __syncthreads();
        const bf16x8 pa = *(const bf16x8*)&P[(jc * 64 + 16 * w + fr) * PLD + fo];
#pragma unroll
        for (int hf = 0; hf < 16; ++hf) {
            const bf16x8 bk = *(const bf16x8*)&KT[(hf * 16 + fr) * KTLD + fo];
            cacc[hf] = __builtin_amdgcn_mfma_f32_16x16x32_bf16(pa, bk, cacc[hf], 0, 0, 0);
        }
    }

#pragma unroll
    for (int hf = 0; hf < 16; ++hf)
#pragma unroll
        for (int r = 0; r < 4; ++r) {
            const int i = 16 * w + rg * 4 + r;
            c_att[(kbase + t0 + i) * (size_t)Hq + hf * 16 + fr] = (bf16_t)cacc[hf][r];
        }
}

// ---------------------------------------------------------------------------
extern "C" void kernel_launch(void* const* d_in, const int* in_sizes, int n_in,
                              void* d_out, int out_size, void* d_ws, size_t ws_size,
                              hipStream_t stream)
{
    (void)in_sizes; (void)n_in; (void)out_size; (void)ws_size;
    const float* x        = (const float*)d_in[0];
    const float* feat_w   = (const float*)d_in[1];
    const float* feat_b   = (const float*)d_in[2];
    const float* k_Wih    = (const float*)d_in[3];
    const float* k_Whh    = (const float*)d_in[4];
    const float* k_bih    = (const float*)d_in[5];
    const float* k_bhh    = (const float*)d_in[6];
    const float* q_Wih    = (const float*)d_in[7];
    const float* q_Whh    = (const float*)d_in[8];
    const float* q_bih    = (const float*)d_in[9];
    const float* q_bhh    = (const float*)d_in[10];
    const float* score_w  = (const float*)d_in[11];
    const float* enhance_w= (const float*)d_in[12];
    const float* enhance_b= (const float*)d_in[13];
    const float* mask_w   = (const float*)d_in[14];
    const float* mask_b   = (const float*)d_in[15];

    float* out0 = (float*)d_out;                         // (8,2048,257)
    float* out1 = out0 + (size_t)Bq * Tq * Fq;           // (8,2048,2048)

    // ---- workspace ----
    float* cst      = (float*)d_ws;                      // 2*TH f32 (c states)
    float* bias_all = cst + (size_t)2 * TH;              // 2048 f32
    float* xp       = bias_all + 2048;                   // Mq*2048 f32 (134 MB)
    bf16_t* cvd = (bf16_t*)(xp + (size_t)Mq * 2048);
    bf16_t* xbf     = cvd;                               // reused as qsbf later
    bf16_t* featw   = cvd + CV_O1;
    bf16_t* Wih_all = cvd + CV_O2;
    bf16_t* Whh_all = cvd + CV_O3;
    bf16_t* scw     = cvd + CV_O4;
    bf16_t* enw     = cvd + CV_O5;
    bf16_t* mkw     = cvd + CV_O6;
    bf16_t* hfeatbf = cvd + CV_TOT;                      // Mq*256 (reused as out_h)
    bf16_t* hkbf    = hfeatbf + (size_t)Mq * Hq;         // 8*TH
    bf16_t* hqbf    = hkbf + (size_t)Bq * TH;            // 8*TH
    bf16_t* cattb   = hqbf + (size_t)Bq * TH;            // Mq*256

    float* ck = cst;
    float* cq = cst + TH;

    hipMemsetAsync(cst, 0, (size_t)2 * TH * sizeof(float), stream);

    cvt_all<<<CV_TOT / 8 / 256, 256, 0, stream>>>(
        x, feat_w, k_Wih, k_Whh, q_Wih, q_Whh, score_w, enhance_w, mask_w, cvd);
    bias_fold<<<8, 256, 0, stream>>>(k_bih, k_bhh, q_bih, q_bhh, bias_all);

    // 1) feat: hfeatbf = tanh(x @ feat_w^T + feat_b)   grid (2, 256)
    gemm_mfma<1, false, true, false><<<dim3(2, Mq / 64), 256, 0, stream>>>(
        xbf, 288, 288, nullptr, 0, 0, featw, feat_b, nullptr, 0,
        nullptr, hfeatbf, Hq, 1 << 30);

    // 2a) xp = hfeat @ [k_Wih;q_Wih]^T + biases  grid (16, 256) = 4096 blocks
    gemm_mfma<0, false, false, true><<<dim3(16, Mq / 64), 256, 0, stream>>>(
        hfeatbf, Hq, Hq, nullptr, 0, 0, Wih_all, bias_all, nullptr, 0,
        xp, nullptr, 2048, 2048);

    // 2b) 8 recurrence steps (Whh only, K=256)
    for (int b = 0; b < Bq; ++b) {
        const bf16_t* pk = b ? hkbf + (size_t)(b - 1) * TH : nullptr;
        const bf16_t* pq = b ? hqbf + (size_t)(b - 1) * TH : nullptr;
        lstm_step<<<dim3(8, Tq / 64, 2), 256, 0, stream>>>(
            pk, pq, Whh_all, xp + (size_t)b * Tq * 2048, ck, cq,
            hkbf + (size_t)b * TH, hqbf + (size_t)b * TH);
    }

    // 3) score: qsbf = q @ score_w^T  (bf16, reuses xbf)  grid (2, 256)
    bf16_t* qsbf = xbf;
    gemm_mfma<0, false, true, false><<<dim3(2, Mq / 64), 256, 0, stream>>>(
        hqbf, Hq, Hq, nullptr, 0, 0, scw, nullptr, nullptr, 0,
        nullptr, qsbf, Hq, 1 << 30);

    // 4+5) fused banded softmax + PV; writes full out1 rows
    band_fused<<<dim3(Tq / 64, Bq), 256, 0, stream>>>(qsbf, hkbf, out1, cattb);

    // 6) enhance: out_h = tanh([c, q] @ enhance_w^T + b)  grid (2, 256)
    bf16_t* outh = hfeatbf;
    gemm_mfma<1, false, true, false><<<dim3(2, Mq / 64), 256, 0, stream>>>(
        cattb, Hq, Hq, hqbf, Hq, Hq, enw, enhance_b, nullptr, 0,
        nullptr, outh, Hq, 1 << 30);

    // 7) mask + final: out0 = x * sigmoid(out_h @ mask_w^T + mask_b)  grid (3, 256)
    gemm_mfma<2, true, false, true><<<dim3(3, Mq / 64), 256, 0, stream>>>(
        outh, Hq, Hq, nullptr, 0, 0, mkw, mask_b, x, Fq,
        out0, nullptr, Fq, Fq);
}

// Round 8
// 209.920 us; speedup vs baseline: 1.6369x; 1.2105x over previous
//
#include <hip/hip_runtime.h>
#include <math.h>

// ---------------------------------------------------------------------------
// AttentionModel on MI355X. Round 8:
//  - NO fill/memset dispatches (runtime fillBufferAligned measured 48 GB/s:
//    4MB memset cost ~86us in-graph). b=0 lstm_step writes c without reading.
//  - xp GEMM eliminated: lstm_step does K=512 (hfeat||h_prev) pipelined,
//    cell fused in epilogue. Saves 268MB ws round-trip + one GEMM.
//  - bias folding merged into cvt_all (one fewer dispatch).
// ---------------------------------------------------------------------------

#define Bq 8
#define Tq 2048
#define Fq 257
#define Hq 256
#define TH (Tq*Hq)       // 524288
#define KW 192           // k-window rows per 64-row t-tile
#define PLD 40           // P row stride (bf16)
#define KTLD 40          // KT row stride (bf16)
#define Mq (Bq*Tq)       // 16384

typedef __bf16 bf16_t;
typedef __bf16 bf16x8 __attribute__((ext_vector_type(8)));
typedef float f32x4 __attribute__((ext_vector_type(4)));

__device__ __forceinline__ float sigf(float x) { return 1.0f / (1.0f + __expf(-x)); }
__device__ __forceinline__ float tanh_f(float x) { return 1.0f - 2.0f / (__expf(2.0f * x) + 1.0f); }

// ------------------- batched fp32 -> bf16 convert + bias fold ---------------
#define CV_X   (Mq*288)            // x padded 257->288
#define CV_FW  (256*288)           // feat_w padded
#define CV_WK  (1024*512)          // [k_Wih | k_Whh]  rows g*256+j
#define CV_WQ  (1024*512)          // [q_Wih | q_Whh]
#define CV_SC  (256*256)
#define CV_EN  (256*512)
#define CV_MK  (384*256)           // mask_w padded rows 257->384
#define CV_O1  CV_X
#define CV_O2  (CV_O1+CV_FW)
#define CV_O3  (CV_O2+CV_WK)
#define CV_O4  (CV_O3+CV_WQ)
#define CV_O5  (CV_O4+CV_SC)
#define CV_O6  (CV_O5+CV_EN)
#define CV_TOT (CV_O6+CV_MK)       // 6,135,808 = 2996 * 2048
#define CVB    (CV_TOT/8/256)      // 2996 data blocks; block CVB = bias fold

__global__ __launch_bounds__(256) void cvt_all(
    const float* __restrict__ x, const float* __restrict__ feat_w,
    const float* __restrict__ kWih, const float* __restrict__ kWhh,
    const float* __restrict__ qWih, const float* __restrict__ qWhh,
    const float* __restrict__ scorew, const float* __restrict__ enhw,
    const float* __restrict__ maskw, bf16_t* __restrict__ dst,
    const float* __restrict__ kbih, const float* __restrict__ kbhh,
    const float* __restrict__ qbih, const float* __restrict__ qbhh,
    float* __restrict__ bias_all)
{
    if (blockIdx.x == CVB) {       // bias fold: 2048 f32
        const int i0 = threadIdx.x * 8;
#pragma unroll
        for (int e = 0; e < 8; ++e) {
            const int i = i0 + e;
            bias_all[i] = (i < 1024) ? kbih[i] + kbhh[i]
                                     : qbih[i - 1024] + qbhh[i - 1024];
        }
        return;
    }
    const int base = (blockIdx.x * 256 + threadIdx.x) * 8;
    bf16_t v[8];
#pragma unroll
    for (int e = 0; e < 8; ++e) {
        const int i = base + e;
        float f;
        if (i < CV_O1)      { const int r = i / 288, c = i - r * 288;
                              f = (c < Fq) ? x[(size_t)r * Fq + c] : 0.0f; }
        else if (i < CV_O2) { const int i2 = i - CV_O1, r = i2 / 288, c = i2 - r * 288;
                              f = (c < Fq) ? feat_w[r * Fq + c] : 0.0f; }
        else if (i < CV_O3) { const int i2 = i - CV_O2, r = i2 >> 9, c = i2 & 511;
                              f = (c < 256) ? kWih[r * 256 + c] : kWhh[r * 256 + c - 256]; }
        else if (i < CV_O4) { const int i2 = i - CV_O3, r = i2 >> 9, c = i2 & 511;
                              f = (c < 256) ? qWih[r * 256 + c] : qWhh[r * 256 + c - 256]; }
        else if (i < CV_O5) { f = scorew[i - CV_O4]; }
        else if (i < CV_O6) { f = enhw[i - CV_O5]; }
        else                { const int i2 = i - CV_O6, r = i2 >> 8, c = i2 & 255;
                              f = (r < Fq) ? maskw[r * 256 + c] : 0.0f; }
        v[e] = (bf16_t)f;
    }
    *(bf16x8*)(dst + base) = *(bf16x8*)v;
}

// ---------------- bf16 MFMA NT GEMM, 64x128 tile, pipelined -----------------
__device__ __forceinline__ const bf16_t* seg_ptr(
    const bf16_t* __restrict__ A1, int lda1, int K1,
    const bf16_t* __restrict__ A2, int lda2, int row, int k, int col8)
{
    return (k < K1) ? A1 + (size_t)row * lda1 + k + col8
                    : A2 + (size_t)row * lda2 + (k - K1) + col8;
}

template<int ACT, bool MULX, bool BF16OUT, bool F32OUT>
__global__ __launch_bounds__(256) void gemm_mfma(
    const bf16_t* __restrict__ A1, int lda1, int K1,
    const bf16_t* __restrict__ A2, int lda2, int K2,
    const bf16_t* __restrict__ W,
    const float* __restrict__ bias,
    const float* __restrict__ xm, int ldx,
    float* __restrict__ out, bf16_t* __restrict__ outbf, int ldo, int Nlog)
{
    __shared__ __align__(16) bf16_t As[64 * 32];     // 4 KB
    __shared__ __align__(16) bf16_t Ws[128 * 32];    // 8 KB
    const int tid = threadIdx.x;
    const int lane = tid & 63;
    const int wave = tid >> 6;
    const int wr = wave >> 1, wc = wave & 1;
    const int fr = lane & 15;
    const int fo = (lane >> 4) * 8;
    const int srow = tid >> 2;
    const int scol = (tid & 3) * 8;
    const int m0 = blockIdx.y * 64, n0 = blockIdx.x * 128;

    const int K = K1 + K2;
    const int ldw = K;

    uint4 ar = *(const uint4*)seg_ptr(A1, lda1, K1, A2, lda2, m0 + srow, 0, scol);
    uint4 w0 = *(const uint4*)(W + (size_t)(n0 + srow)      * ldw + scol);
    uint4 w1 = *(const uint4*)(W + (size_t)(n0 + srow + 64) * ldw + scol);

    f32x4 acc[2][4] = {};
    for (int k0 = 0; k0 < K; k0 += 32) {
        __syncthreads();                // prior LDS reads done
        *(uint4*)&As[srow * 32 + scol]        = ar;
        *(uint4*)&Ws[srow * 32 + scol]        = w0;
        *(uint4*)&Ws[(srow + 64) * 32 + scol] = w1;
        if (k0 + 32 < K) {              // prefetch k+1 (hides under MFMA below)
            ar = *(const uint4*)seg_ptr(A1, lda1, K1, A2, lda2, m0 + srow, k0 + 32, scol);
            w0 = *(const uint4*)(W + (size_t)(n0 + srow)      * ldw + k0 + 32 + scol);
            w1 = *(const uint4*)(W + (size_t)(n0 + srow + 64) * ldw + k0 + 32 + scol);
        }
        __syncthreads();
        bf16x8 af[2], bfr[4];
#pragma unroll
        for (int i = 0; i < 2; ++i) af[i]  = *(const bf16x8*)&As[(wr * 32 + i * 16 + fr) * 32 + fo];
#pragma unroll
        for (int j = 0; j < 4; ++j) bfr[j] = *(const bf16x8*)&Ws[(wc * 64 + j * 16 + fr) * 32 + fo];
#pragma unroll
        for (int i = 0; i < 2; ++i)
#pragma unroll
            for (int j = 0; j < 4; ++j)
                acc[i][j] = __builtin_amdgcn_mfma_f32_16x16x32_bf16(af[i], bfr[j], acc[i][j], 0, 0, 0);
    }

    const int rbase = (lane >> 4) * 4;
#pragma unroll
    for (int i = 0; i < 2; ++i) {
#pragma unroll
        for (int j = 0; j < 4; ++j) {
            const int n = n0 + wc * 64 + j * 16 + fr;
            if (n >= Nlog) continue;
            const float bv = bias ? bias[n] : 0.0f;
            const int m = m0 + wr * 32 + i * 16 + rbase;
#pragma unroll
            for (int r = 0; r < 4; ++r) {
                float v = acc[i][j][r] + bv;
                if (ACT == 1) v = tanh_f(v);
                else if (ACT == 2) v = sigf(v);
                if (MULX) v *= xm[(size_t)(m + r) * ldx + n];
                if (F32OUT) out[(size_t)(m + r) * ldo + n] = v;
                if (BF16OUT) outbf[(size_t)(m + r) * ldo + n] = (bf16_t)v;
            }
        }
    }
}

// -------- LSTM step: gates = hfeat@Wih^T + hprev@Whh^T + bias, cell fused ----
// 64 rows x (32 j x 4 gates) per block; grid (8, 32, 2) = 512 blocks.
// W rows: z*1024 + g*256 + j, cols [Wih(256)|Whh(256)]. Pipelined K-loop.
// FIRST: c_prev = 0 -> no c read (harness-poison safe), skip Whh half.
template<bool FIRST>
__global__ __launch_bounds__(256) void lstm_step(
    const bf16_t* __restrict__ hfb,                                   // hfeat + b*TH
    const bf16_t* __restrict__ hkp, const bf16_t* __restrict__ hqp,   // prev h
    const bf16_t* __restrict__ Wall, const float* __restrict__ bias_all,
    float* __restrict__ cst,
    bf16_t* __restrict__ hk, bf16_t* __restrict__ hq)
{
    __shared__ __align__(16) bf16_t As[64 * 32];    // 4 KB
    __shared__ __align__(16) bf16_t Ws[128 * 32];   // 8 KB
    const int z = blockIdx.z;
    const bf16_t* hprev = z ? hqp : hkp;
    const bf16_t* Wz = Wall + (size_t)z * (1024 * 512);
    float* c     = cst + (size_t)z * TH;
    bf16_t* hout = z ? hq : hk;

    const int tid = threadIdx.x, lane = tid & 63, wave = tid >> 6;
    const int wr = wave >> 1, wc = wave & 1;
    const int fr = lane & 15, rg = lane >> 4, fo = rg * 8;
    const int m0 = blockIdx.y * 64;
    const int jb = blockIdx.x * 32;

    const int s0 = tid >> 2, acol = (tid & 3) * 8;
    const int s1 = s0 + 64;
    const int wn0 = ((s0 >> 5) * 256) + jb + (s0 & 31);   // gate-major strips
    const int wn1 = ((s1 >> 5) * 256) + jb + (s1 & 31);

    constexpr int NIT = FIRST ? 8 : 16;   // K = 256 (Wih only) or 512

    f32x4 acc[2][4] = {};

    uint4 ar  = *(const uint4*)(hfb + (size_t)(m0 + s0) * Hq + acol);
    uint4 w0r = *(const uint4*)(Wz + (size_t)wn0 * 512 + acol);
    uint4 w1r = *(const uint4*)(Wz + (size_t)wn1 * 512 + acol);
#pragma unroll
    for (int t = 0; t < NIT; ++t) {
        if (t) __syncthreads();                  // prior LDS reads done
        *(uint4*)&As[s0 * 32 + acol] = ar;
        *(uint4*)&Ws[s0 * 32 + acol] = w0r;
        *(uint4*)&Ws[s1 * 32 + acol] = w1r;
        if (t + 1 < NIT) {                       // prefetch next k-slice
            const int tn = t + 1;
            ar  = (tn < 8)
                ? *(const uint4*)(hfb   + (size_t)(m0 + s0) * Hq + tn * 32 + acol)
                : *(const uint4*)(hprev + (size_t)(m0 + s0) * Hq + (tn - 8) * 32 + acol);
            w0r = *(const uint4*)(Wz + (size_t)wn0 * 512 + tn * 32 + acol);
            w1r = *(const uint4*)(Wz + (size_t)wn1 * 512 + tn * 32 + acol);
        }
        __syncthreads();
        bf16x8 af[2], bg[4];
#pragma unroll
        for (int i = 0; i < 2; ++i) af[i] = *(const bf16x8*)&As[(wr * 32 + i * 16 + fr) * 32 + fo];
#pragma unroll
        for (int g = 0; g < 4; ++g) bg[g] = *(const bf16x8*)&Ws[(g * 32 + wc * 16 + fr) * 32 + fo];
#pragma unroll
        for (int i = 0; i < 2; ++i)
#pragma unroll
            for (int g = 0; g < 4; ++g)
                acc[i][g] = __builtin_amdgcn_mfma_f32_16x16x32_bf16(af[i], bg[g], acc[i][g], 0, 0, 0);
    }

    // cell epilogue: thread owns 4 gates of column j for 8 rows
    const int j = jb + wc * 16 + fr;
    float bs[4];
#pragma unroll
    for (int g = 0; g < 4; ++g) bs[g] = bias_all[z * 1024 + g * 256 + j];
#pragma unroll
    for (int i = 0; i < 2; ++i)
#pragma unroll
        for (int r = 0; r < 4; ++r) {
            const int t = m0 + wr * 32 + i * 16 + rg * 4 + r;
            const size_t ix = (size_t)t * Hq + j;
            const float gi = acc[i][0][r] + bs[0];
            const float gf = acc[i][1][r] + bs[1];
            const float gg = acc[i][2][r] + bs[2];
            const float go = acc[i][3][r] + bs[3];
            const float cn = FIRST ? sigf(gi) * tanh_f(gg)
                                   : sigf(gf) * c[ix] + sigf(gi) * tanh_f(gg);
            c[ix] = cn;
            hout[ix] = (bf16_t)(sigf(go) * tanh_f(cn));
        }
}

// ----------------------- fused banded attention (unchanged) -----------------
__global__ __launch_bounds__(256) void band_fused(
    const bf16_t* __restrict__ qsbf, const bf16_t* __restrict__ kbf,
    float* __restrict__ out1, bf16_t* __restrict__ c_att)
{
    __shared__ __align__(16) bf16_t Ks[8 * KW * 32];     // 98304 B, [h/32][j][32]
    __shared__ __align__(16) bf16_t P[6 * 64 * PLD];     // 30720 B
    __shared__ __align__(16) bf16_t KT[256 * KTLD];      // 20480 B

    const int b = blockIdx.y;
    const int t0 = blockIdx.x * 64;
    const int u0 = t0 - 128;
    const int tid = threadIdx.x, lane = tid & 63, w = tid >> 6;
    const int fr = lane & 15, rg = lane >> 4, fo = rg * 8;
    const size_t kbase = (size_t)b * Tq;

#pragma unroll
    for (int it = 0; it < 24; ++it) {
        const int idx = it * 256 + tid;
        const int n  = idx >> 5;
        const int c8 = (idx & 31) * 8;
        uint4 v = {0, 0, 0, 0};
        const int u = u0 + n;
        if (u >= 0) v = *(const uint4*)(kbf + (kbase + u) * (size_t)Hq + c8);
        *(uint4*)&Ks[((c8 >> 5) * KW + n) * 32 + (c8 & 31)] = v;
    }
    __syncthreads();

    f32x4 acc[12] = {};
    const bf16_t* qrow = qsbf + (kbase + t0 + 16 * w + fr) * (size_t)Hq;
#pragma unroll
    for (int ks = 0; ks < 8; ++ks) {
        const bf16x8 aq = *(const bf16x8*)(qrow + ks * 32 + fo);
#pragma unroll
        for (int jf = 0; jf < 12; ++jf) {
            const bf16x8 bk = *(const bf16x8*)&Ks[(ks * KW + jf * 16 + fr) * 32 + fo];
            acc[jf] = __builtin_amdgcn_mfma_f32_16x16x32_bf16(aq, bk, acc[jf], 0, 0, 0);
        }
    }

    const int jmin = (128 - t0) > 0 ? (128 - t0) : 0;
    float mx[4] = {-3e38f, -3e38f, -3e38f, -3e38f};
#pragma unroll
    for (int jf = 0; jf < 12; ++jf)
#pragma unroll
        for (int r = 0; r < 4; ++r) {
            const int i = 16 * w + rg * 4 + r;
            const int j = jf * 16 + fr;
            if (j >= i && j <= i + 128 && j >= jmin)
                mx[r] = fmaxf(mx[r], acc[jf][r]);
        }
#pragma unroll
    for (int d = 1; d < 16; d <<= 1)
#pragma unroll
        for (int r = 0; r < 4; ++r) mx[r] = fmaxf(mx[r], __shfl_xor(mx[r], d));

    float ex[12][4];
    float sm[4] = {0.0f, 0.0f, 0.0f, 0.0f};
#pragma unroll
    for (int jf = 0; jf < 12; ++jf)
#pragma unroll
        for (int r = 0; r < 4; ++r) {
            const int i = 16 * w + rg * 4 + r;
            const int j = jf * 16 + fr;
            const bool v = (j >= i && j <= i + 128 && j >= jmin);
            const float e = v ? __expf(acc[jf][r] - mx[r]) : 0.0f;
            ex[jf][r] = e;
            sm[r] += e;
        }
#pragma unroll
    for (int d = 1; d < 16; d <<= 1)
#pragma unroll
        for (int r = 0; r < 4; ++r) sm[r] += __shfl_xor(sm[r], d);
    float inv[4];
#pragma unroll
    for (int r = 0; r < 4; ++r) inv[r] = 1.0f / (sm[r] + 1e-10f);

#pragma unroll
    for (int jf = 0; jf < 12; ++jf)
#pragma unroll
        for (int r = 0; r < 4; ++r) {
            const int i = 16 * w + rg * 4 + r;
            const int j = jf * 16 + fr;
            const float wv = ex[jf][r] * inv[r];
            if (u0 + j >= 0)
                out1[(kbase + t0 + i) * (size_t)Tq + (u0 + j)] = wv;
            P[((j >> 5) * 64 + i) * PLD + (j & 31)] = (bf16_t)wv;
        }

    {
        const int c4l = (u0 > 0 ? u0 : 0) >> 2;
        const int c4r = (u0 + KW) >> 2;
        const float4 z4 = {0.0f, 0.0f, 0.0f, 0.0f};
        for (int rr = 0; rr < 16; ++rr) {
            float* rowp = out1 + (kbase + t0 + 16 * w + rr) * (size_t)Tq;
            for (int c4 = lane; c4 < c4l; c4 += 64)
                *(float4*)(rowp + 4 * c4) = z4;
            for (int c4 = c4r + lane; c4 < Tq / 4; c4 += 64)
                *(float4*)(rowp + 4 * c4) = z4;
        }
    }

    f32x4 cacc[16] = {};
    for (int jc = 0; jc < 6; ++jc) {
        __syncthreads();
#pragma unroll
        for (int it = 0; it < 4; ++it) {
            const int idx = it * 256 + tid;
            const int jl = idx >> 5;
            const int hc = (idx & 31) * 8;
            const bf16x8 kv = *(const bf16x8*)&Ks[((hc >> 5) * KW + jc * 32 + jl) * 32 + (hc & 31)];
#pragma unroll
            for (int e = 0; e < 8; ++e) KT[(hc + e) * KTLD + jl] = kv[e];
        }
        __syncthreads();
        const bf16x8 pa = *(const bf16x8*)&P[(jc * 64 + 16 * w + fr) * PLD + fo];
#pragma unroll
        for (int hf = 0; hf < 16; ++hf) {
            const bf16x8 bk = *(const bf16x8*)&KT[(hf * 16 + fr) * KTLD + fo];
            cacc[hf] = __builtin_amdgcn_mfma_f32_16x16x32_bf16(pa, bk, cacc[hf], 0, 0, 0);
        }
    }

#pragma unroll
    for (int hf = 0; hf < 16; ++hf)
#pragma unroll
        for (int r = 0; r < 4; ++r) {
            const int i = 16 * w + rg * 4 + r;
            c_att[(kbase + t0 + i) * (size_t)Hq + hf * 16 + fr] = (bf16_t)cacc[hf][r];
        }
}

// ---------------------------------------------------------------------------
extern "C" void kernel_launch(void* const* d_in, const int* in_sizes, int n_in,
                              void* d_out, int out_size, void* d_ws, size_t ws_size,
                              hipStream_t stream)
{
    (void)in_sizes; (void)n_in; (void)out_size; (void)ws_size;
    const float* x        = (const float*)d_in[0];
    const float* feat_w   = (const float*)d_in[1];
    const float* feat_b   = (const float*)d_in[2];
    const float* k_Wih    = (const float*)d_in[3];
    const float* k_Whh    = (const float*)d_in[4];
    const float* k_bih    = (const float*)d_in[5];
    const float* k_bhh    = (const float*)d_in[6];
    const float* q_Wih    = (const float*)d_in[7];
    const float* q_Whh    = (const float*)d_in[8];
    const float* q_bih    = (const float*)d_in[9];
    const float* q_bhh    = (const float*)d_in[10];
    const float* score_w  = (const float*)d_in[11];
    const float* enhance_w= (const float*)d_in[12];
    const float* enhance_b= (const float*)d_in[13];
    const float* mask_w   = (const float*)d_in[14];
    const float* mask_b   = (const float*)d_in[15];

    float* out0 = (float*)d_out;                         // (8,2048,257)
    float* out1 = out0 + (size_t)Bq * Tq * Fq;           // (8,2048,2048)

    // ---- workspace (no fills needed; every word written before read) ----
    float* cst      = (float*)d_ws;                      // 2*TH f32 (c states)
    float* bias_all = cst + (size_t)2 * TH;              // 2048 f32
    bf16_t* cvd = (bf16_t*)(bias_all + 2048);
    bf16_t* xbf     = cvd;                               // reused as qsbf later
    bf16_t* featw   = cvd + CV_O1;
    bf16_t* Wall    = cvd + CV_O2;                       // 2048 rows x 512 [k;q]
    bf16_t* scw     = cvd + CV_O4;
    bf16_t* enw     = cvd + CV_O5;
    bf16_t* mkw     = cvd + CV_O6;
    bf16_t* hfeatbf = cvd + CV_TOT;                      // Mq*256 (reused as out_h)
    bf16_t* hkbf    = hfeatbf + (size_t)Mq * Hq;         // 8*TH
    bf16_t* hqbf    = hkbf + (size_t)Bq * TH;            // 8*TH
    bf16_t* cattb   = hqbf + (size_t)Bq * TH;            // Mq*256

    // 0) conversions + bias fold (one dispatch)
    cvt_all<<<CVB + 1, 256, 0, stream>>>(
        x, feat_w, k_Wih, k_Whh, q_Wih, q_Whh, score_w, enhance_w, mask_w, cvd,
        k_bih, k_bhh, q_bih, q_bhh, bias_all);

    // 1) feat: hfeatbf = tanh(x @ feat_w^T + feat_b)   grid (2, 256)
    gemm_mfma<1, false, true, false><<<dim3(2, Mq / 64), 256, 0, stream>>>(
        xbf, 288, 288, nullptr, 0, 0, featw, feat_b, nullptr, 0,
        nullptr, hfeatbf, Hq, 1 << 30);

    // 2) LSTM k & q: 8 fused steps (K=512; b=0 writes c without reading)
    lstm_step<true><<<dim3(8, Tq / 64, 2), 256, 0, stream>>>(
        hfeatbf, nullptr, nullptr, Wall, bias_all, cst, hkbf, hqbf);
    for (int b = 1; b < Bq; ++b)
        lstm_step<false><<<dim3(8, Tq / 64, 2), 256, 0, stream>>>(
            hfeatbf + (size_t)b * TH,
            hkbf + (size_t)(b - 1) * TH, hqbf + (size_t)(b - 1) * TH,
            Wall, bias_all, cst,
            hkbf + (size_t)b * TH, hqbf + (size_t)b * TH);

    // 3) score: qsbf = q @ score_w^T  (bf16, reuses xbf)  grid (2, 256)
    bf16_t* qsbf = xbf;
    gemm_mfma<0, false, true, false><<<dim3(2, Mq / 64), 256, 0, stream>>>(
        hqbf, Hq, Hq, nullptr, 0, 0, scw, nullptr, nullptr, 0,
        nullptr, qsbf, Hq, 1 << 30);

    // 4+5) fused banded softmax + PV; writes full out1 rows
    band_fused<<<dim3(Tq / 64, Bq), 256, 0, stream>>>(qsbf, hkbf, out1, cattb);

    // 6) enhance: out_h = tanh([c, q] @ enhance_w^T + b)  grid (2, 256)
    bf16_t* outh = hfeatbf;
    gemm_mfma<1, false, true, false><<<dim3(2, Mq / 64), 256, 0, stream>>>(
        cattb, Hq, Hq, hqbf, Hq, Hq, enw, enhance_b, nullptr, 0,
        nullptr, outh, Hq, 1 << 30);

    // 7) mask + final: out0 = x * sigmoid(out_h @ mask_w^T + mask_b)  grid (3, 256)
    gemm_mfma<2, true, false, true><<<dim3(3, Mq / 64), 256, 0, stream>>>(
        outh, Hq, Hq, nullptr, 0, 0, mkw, mask_b, x, Fq,
        out0, nullptr, Fq, Fq);
}